// Round 1
// baseline (115.985 us; speedup 1.0000x reference)
//
#include <hip/hip_runtime.h>
#include <stdint.h>

// triplet_loss_cl: loss = mean_i(-log(softmax(q G^T)[i,i] + 1e-5)), N=8192, D=256.
// Flash-style: never materialize logits. Fixed offset 64 instead of online max
// (logits bounded; offset cancels exactly in p = exp(l_ii-64)/sum exp(l-64)).

#define DDIM  256
#define PITCH 528              // LDS row pitch bytes (512 + 16 pad -> 2-way banks, free)
#define LOG2E 1.44269504f
#define KOFF  92.3324826f      // 64 * log2(e); same literal everywhere so it cancels

typedef __attribute__((ext_vector_type(8))) short short8;  // 8 bf16 (4 VGPRs)
typedef __attribute__((ext_vector_type(4))) float f32x4;

__device__ __forceinline__ uint32_t pack2bf(float lo, float hi) {
    // [bf16(hi) : bf16(lo)] via v_perm (truncation; bias negligible here, and any
    // within-pair order quirk applies identically to A and B -> dot invariant)
    return __builtin_amdgcn_perm(__float_as_uint(hi), __float_as_uint(lo), 0x07060302u);
}

// ---- kernel 0: g fp32 -> packed bf16 in workspace ----
__global__ __launch_bounds__(256) void k_cvt(const float* __restrict__ g,
                                             uint32_t* __restrict__ gb) {
    int idx = blockIdx.x * 256 + threadIdx.x;      // 262144 threads, 8 elems each
    const float4* g4 = (const float4*)g;
    float4 a = g4[2 * idx], b = g4[2 * idx + 1];
    uint4 o;
    o.x = pack2bf(a.x, a.y);
    o.y = pack2bf(a.z, a.w);
    o.z = pack2bf(b.x, b.y);
    o.w = pack2bf(b.z, b.w);
    ((uint4*)gb)[idx] = o;
}

// ---- kernel 1: per-row Z partials (+ diagonal logits) ----
// grid 512 = 64 row-tiles (128 rows) x 8 col-splits (1024 cols); cs = blockIdx&7 (XCD affinity)
__global__ __launch_bounds__(256, 2) void k_main(const float* __restrict__ q,
                                                 const uint32_t* __restrict__ gb,
                                                 float* __restrict__ zpart,
                                                 float* __restrict__ diag) {
    __shared__ char lds[64 * PITCH];               // one 64x256 bf16 G tile, padded
    const int tid  = threadIdx.x;
    const int wave = tid >> 6;
    const int lane = tid & 63;
    const int l15  = lane & 15;
    const int quad = lane >> 4;
    const int t    = blockIdx.x >> 3;
    const int cs   = blockIdx.x & 7;
    const int col0 = cs << 10;
    const int rowbase = t * 128 + wave * 32;       // wave owns 32 rows (2 rowgroups)

    // A fragments (q rows) held in registers for the whole kernel: 64 VGPRs
    short8 afrag[2][8];
#pragma unroll
    for (int rg = 0; rg < 2; ++rg) {
        const float* qr = q + (rowbase + rg * 16 + l15) * DDIM + quad * 8;
#pragma unroll
        for (int ks = 0; ks < 8; ++ks) {
            float4 lo = *(const float4*)(qr + ks * 32);
            float4 hi = *(const float4*)(qr + ks * 32 + 4);
            union { uint32_t u[4]; short8 s; } cv;
            cv.u[0] = pack2bf(lo.x, lo.y);
            cv.u[1] = pack2bf(lo.z, lo.w);
            cv.u[2] = pack2bf(hi.x, hi.y);
            cv.u[3] = pack2bf(hi.z, hi.w);
            afrag[rg][ks] = cv.s;
        }
    }

    float zacc[2][4];
#pragma unroll
    for (int rg = 0; rg < 2; ++rg)
#pragma unroll
        for (int r = 0; r < 4; ++r) zacc[rg][r] = 0.f;

    const bool blk_diag = (cs == (t >> 3));

    for (int jt = 0; jt < 16; ++jt) {
        const int jrow0 = col0 + jt * 64;
        // stage 64x256 bf16 tile: 2048 x 16B chunks, 8 per thread, coalesced
#pragma unroll
        for (int i = 0; i < 8; ++i) {
            int p = i * 256 + tid;
            int r = p >> 5, c = p & 31;
            uint4 v = *(const uint4*)(gb + (jrow0 + r) * 128 + c * 4);
            *(uint4*)(lds + r * PITCH + c * 16) = v;
        }
        __syncthreads();

        f32x4 acc[2][4];
#pragma unroll
        for (int rg = 0; rg < 2; ++rg)
#pragma unroll
            for (int cf = 0; cf < 4; ++cf) acc[rg][cf] = (f32x4){0.f, 0.f, 0.f, 0.f};

#pragma unroll
        for (int ks = 0; ks < 8; ++ks) {
#pragma unroll
            for (int cf = 0; cf < 4; ++cf) {
                short8 b = *(const short8*)(lds + (cf * 16 + l15) * PITCH + ks * 64 + quad * 16);
                acc[0][cf] = __builtin_amdgcn_mfma_f32_16x16x32_bf16(afrag[0][ks], b, acc[0][cf], 0, 0, 0);
                acc[1][cf] = __builtin_amdgcn_mfma_f32_16x16x32_bf16(afrag[1][ks], b, acc[1][cf], 0, 0, 0);
            }
        }

        // epilogue: Z += sum exp(l - 64). C/D layout: col=lane&15, row=quad*4+reg (m89/m91)
#pragma unroll
        for (int rg = 0; rg < 2; ++rg)
#pragma unroll
            for (int r = 0; r < 4; ++r) {
                float e0 = exp2f(fmaf(acc[rg][0][r], LOG2E, -KOFF));
                float e1 = exp2f(fmaf(acc[rg][1][r], LOG2E, -KOFF));
                float e2 = exp2f(fmaf(acc[rg][2][r], LOG2E, -KOFF));
                float e3 = exp2f(fmaf(acc[rg][3][r], LOG2E, -KOFF));
                zacc[rg][r] += (e0 + e1) + (e2 + e3);
            }

        if (blk_diag && ((jt >> 1) == (t & 7))) {  // this tile contains diagonal cols
#pragma unroll
            for (int rg = 0; rg < 2; ++rg)
#pragma unroll
                for (int cf = 0; cf < 4; ++cf)
#pragma unroll
                    for (int r = 0; r < 4; ++r) {
                        int rowg = rowbase + rg * 16 + quad * 4 + r;
                        int colg = col0 + jt * 64 + cf * 16 + l15;
                        if (rowg == colg) diag[rowg] = acc[rg][cf][r];
                    }
        }
        __syncthreads();
    }

    // fold the 16 column-lane-classes (lanes differing in bits 0..3 share a row)
#pragma unroll
    for (int d = 1; d < 16; d <<= 1)
#pragma unroll
        for (int rg = 0; rg < 2; ++rg)
#pragma unroll
            for (int r = 0; r < 4; ++r)
                zacc[rg][r] += __shfl_xor(zacc[rg][r], d, 64);

    if (l15 == 0) {
#pragma unroll
        for (int rg = 0; rg < 2; ++rg)
#pragma unroll
            for (int r = 0; r < 4; ++r) {
                int rowg = rowbase + rg * 16 + quad * 4 + r;
                zpart[rowg * 8 + cs] = zacc[rg][r];
            }
    }
}

// ---- kernel 2: merge partials, loss = mean(-log(p + 1e-5)) ----
__global__ __launch_bounds__(1024) void k_fin(const float* __restrict__ zpart,
                                              const float* __restrict__ diag,
                                              float* __restrict__ out) {
    __shared__ float red[16];
    int tid = threadIdx.x;
    float sum = 0.f;
#pragma unroll
    for (int i = 0; i < 8; ++i) {
        int r = i * 1024 + tid;
        float4 z0 = *(const float4*)(zpart + r * 8);
        float4 z1 = *(const float4*)(zpart + r * 8 + 4);
        float Z = ((z0.x + z0.y) + (z0.z + z0.w)) + ((z1.x + z1.y) + (z1.z + z1.w));
        float p = exp2f(fmaf(diag[r], LOG2E, -KOFF)) / Z;   // 64-offset cancels exactly
        sum += -logf(p + 1e-5f);
    }
#pragma unroll
    for (int d = 1; d < 64; d <<= 1) sum += __shfl_xor(sum, d, 64);
    if ((tid & 63) == 0) red[tid >> 6] = sum;
    __syncthreads();
    if (tid < 64) {
        float v = (tid < 16) ? red[tid] : 0.f;
        v += __shfl_xor(v, 1, 64);
        v += __shfl_xor(v, 2, 64);
        v += __shfl_xor(v, 4, 64);
        v += __shfl_xor(v, 8, 64);
        if (tid == 0) out[0] = v * (1.f / 8192.f);
    }
}

extern "C" void kernel_launch(void* const* d_in, const int* in_sizes, int n_in,
                              void* d_out, int out_size, void* d_ws, size_t ws_size,
                              hipStream_t stream) {
    const float* q = (const float*)d_in[0];
    const float* g = (const float*)d_in[1];
    char* ws = (char*)d_ws;
    uint32_t* gb = (uint32_t*)ws;                             // 4 MiB: g as bf16
    float* diag  = (float*)(ws + (4u << 20));                 // 32 KiB
    float* zpart = (float*)(ws + (4u << 20) + (32u << 10));   // 256 KiB
    k_cvt <<<1024, 256, 0, stream>>>(g, gb);
    k_main<<<512,  256, 0, stream>>>(q, gb, zpart, diag);
    k_fin <<<1,   1024, 0, stream>>>(zpart, diag, (float*)d_out);
    (void)in_sizes; (void)n_in; (void)out_size; (void)ws_size;
}

// Round 2
// 105.333 us; speedup vs baseline: 1.1011x; 1.1011x over previous
//
#include <hip/hip_runtime.h>
#include <stdint.h>

// triplet_loss_cl: loss = mean_i(-log(softmax(q G^T)[i,i] + 1e-5)), N=8192, D=256.
// Flash-style, never materialize logits. Fixed offset 64 instead of online max
// (logits bounded; offset cancels exactly in p = exp(l_ii-64)/sum exp(l-64)).
//
// Round 2: pre-permute q,g to bf16 "panel-fragment" layout (64-row panels,
// 16B chunks in exact MFMA lane-consume order) -> global_load_lds staging,
// stride-1 LDS reads (no bank conflicts), direct b128 A-fragment loads.
// 64 rows/wave (BM=256) halves LDS-pipe reads; 16 col-splits; parallel finalize.

#define LOG2E 1.44269504f
#define KOFF  92.3324826f          // 64 * log2(e); cancels exactly in p = e_ii/Z

typedef __attribute__((ext_vector_type(8))) short short8;  // 8 bf16
typedef __attribute__((ext_vector_type(4))) float f32x4;

typedef __attribute__((address_space(1))) const uint32_t gu32;
typedef __attribute__((address_space(3))) uint32_t lu32;

__device__ __forceinline__ uint32_t pack2bf(float lo, float hi) {
    return __builtin_amdgcn_perm(__float_as_uint(hi), __float_as_uint(lo), 0x07060302u);
}

// ---- kernel 0: fp32 row-major [8192][256] -> bf16 panel-fragment layout ----
// Panel = 64 rows. Chunk cidx = (ks*4+cf)*64 + quad*16 + l15 holds
// src[64p + cf*16 + l15][ks*32 + quad*8 .. +8). 262144 chunks per array.
__global__ __launch_bounds__(256) void k_cvt(const float* __restrict__ q,
                                             const float* __restrict__ g,
                                             uint4* __restrict__ qb,
                                             uint4* __restrict__ gb) {
    int o = blockIdx.x * 256 + threadIdx.x;        // grid 2048: q then g
    const float* src = q;
    uint4* dst = qb;
    if (o >= 262144) { o -= 262144; src = g; dst = gb; }
    int p   = o >> 11;
    int b   = (o >> 6) & 31;                       // ks*4 + cf
    int l   = o & 63;
    int row = p * 64 + (b & 3) * 16 + (l & 15);
    int k0  = (b >> 2) * 32 + (l >> 4) * 8;
    const float4* s = (const float4*)(src + row * 256 + k0);
    float4 a = s[0], c = s[1];
    uint4 ov;
    ov.x = pack2bf(a.x, a.y); ov.y = pack2bf(a.z, a.w);
    ov.z = pack2bf(c.x, c.y); ov.w = pack2bf(c.z, c.w);
    dst[o] = ov;
}

// ---- kernel 1: per-row Z partials (+ diagonal logits) ----
// grid 512 = 32 row-tiles (BM=256) x 16 col-splits (512 cols). 4 waves,
// each owns 64 rows (4 rowgroups). B staged via global_load_lds per 64-col tile.
__global__ __launch_bounds__(256, 2) void k_main(const uint4* __restrict__ qb,
                                                 const uint4* __restrict__ gb,
                                                 float* __restrict__ zpart,
                                                 float* __restrict__ diag) {
    __shared__ uint4 lds4[2048];                   // 32 KiB: one 64x256 bf16 panel
    char* lds = (char*)lds4;
    const int tid  = threadIdx.x;
    const int wave = tid >> 6;
    const int lane = tid & 63;
    const int l15  = lane & 15;
    const int quad = lane >> 4;
    const int t    = blockIdx.x >> 4;              // row-tile (256 rows)
    const int cs   = blockIdx.x & 15;              // col-split (512 cols)
    const int rowbase = t * 256 + wave * 64;

    // A fragments: rowgroup rg lives in q-panel (4t+wave) at cf=rg. 128 VGPRs.
    short8 afrag[4][8];
    {
        const char* qp = (const char*)qb + (size_t)(t * 4 + wave) * 32768 + (lane << 4);
#pragma unroll
        for (int rg = 0; rg < 4; ++rg)
#pragma unroll
            for (int ks = 0; ks < 8; ++ks)
                afrag[rg][ks] = *(const short8*)(qp + ((ks * 4 + rg) << 10));
    }

    float zacc[4][4];
#pragma unroll
    for (int rg = 0; rg < 4; ++rg)
#pragma unroll
        for (int r = 0; r < 4; ++r) zacc[rg][r] = 0.f;

    const bool bd = (cs == (t >> 1));              // block's col-slice hits diagonal

    for (int jt = 0; jt < 8; ++jt) {
        const char* gp = (const char*)gb + (size_t)(cs * 8 + jt) * 32768;
        // stage 32KB: 4 waves x 8 x 1KB DMA, linear -> linear (LDS dest uniform+lane*16)
        {
            const int off = wave * 8192;
#pragma unroll
            for (int i = 0; i < 8; ++i)
                __builtin_amdgcn_global_load_lds(
                    (gu32*)(gp + off + i * 1024 + (lane << 4)),
                    (lu32*)(lds + off + i * 1024), 16, 0, 0);
        }
        __syncthreads();

        f32x4 acc[4][4];                           // [rg][cf]
#pragma unroll
        for (int rg = 0; rg < 4; ++rg)
#pragma unroll
            for (int cf = 0; cf < 4; ++cf) acc[rg][cf] = (f32x4){0.f, 0.f, 0.f, 0.f};

#pragma unroll
        for (int ks = 0; ks < 8; ++ks)
#pragma unroll
            for (int cf = 0; cf < 4; ++cf) {
                short8 b = *(const short8*)(lds + ((ks * 4 + cf) << 10) + (lane << 4));
#pragma unroll
                for (int rg = 0; rg < 4; ++rg)
                    acc[rg][cf] = __builtin_amdgcn_mfma_f32_16x16x32_bf16(
                        afrag[rg][ks], b, acc[rg][cf], 0, 0, 0);
            }

        // Z += sum exp(l - 64). C/D layout: col=lane&15, row=quad*4+reg (m89/m91)
#pragma unroll
        for (int rg = 0; rg < 4; ++rg)
#pragma unroll
            for (int r = 0; r < 4; ++r) {
                float e0 = __builtin_amdgcn_exp2f(fmaf(acc[rg][0][r], LOG2E, -KOFF));
                float e1 = __builtin_amdgcn_exp2f(fmaf(acc[rg][1][r], LOG2E, -KOFF));
                float e2 = __builtin_amdgcn_exp2f(fmaf(acc[rg][2][r], LOG2E, -KOFF));
                float e3 = __builtin_amdgcn_exp2f(fmaf(acc[rg][3][r], LOG2E, -KOFF));
                zacc[rg][r] += (e0 + e1) + (e2 + e3);
            }

        if (bd && ((jt >> 2) == (t & 1))) {        // tile contains diagonal cols
#pragma unroll
            for (int rg = 0; rg < 4; ++rg)
#pragma unroll
                for (int cf = 0; cf < 4; ++cf)
#pragma unroll
                    for (int r = 0; r < 4; ++r) {
                        int rowg = rowbase + rg * 16 + quad * 4 + r;
                        int colg = (cs << 9) + jt * 64 + cf * 16 + l15;
                        if (rowg == colg) diag[rowg] = acc[rg][cf][r];
                    }
        }
        __syncthreads();
    }

    // fold the 16 column-lane-classes (lanes differing in bits 0..3 share a row)
#pragma unroll
    for (int d = 1; d < 16; d <<= 1)
#pragma unroll
        for (int rg = 0; rg < 4; ++rg)
#pragma unroll
            for (int r = 0; r < 4; ++r)
                zacc[rg][r] += __shfl_xor(zacc[rg][r], d, 64);

    if (l15 == 0) {
#pragma unroll
        for (int rg = 0; rg < 4; ++rg)
#pragma unroll
            for (int r = 0; r < 4; ++r)
                zpart[(rowbase + rg * 16 + quad * 4 + r) * 16 + cs] = zacc[rg][r];
    }
}

// ---- kernel 2a: per-row loss, 32-block tree ----
__global__ __launch_bounds__(256) void k_fin1(const float* __restrict__ zpart,
                                              const float* __restrict__ diag,
                                              float* __restrict__ partial) {
    __shared__ float red[4];
    int r = blockIdx.x * 256 + threadIdx.x;
    const float4* z = (const float4*)(zpart + r * 16);
    float4 a = z[0], b = z[1], c = z[2], d = z[3];
    float Z = (((a.x + a.y) + (a.z + a.w)) + ((b.x + b.y) + (b.z + b.w)))
            + (((c.x + c.y) + (c.z + c.w)) + ((d.x + d.y) + (d.z + d.w)));
    float p = __builtin_amdgcn_exp2f(fmaf(diag[r], LOG2E, -KOFF)) / Z;
    float v = -logf(p + 1e-5f);
#pragma unroll
    for (int dd = 1; dd < 64; dd <<= 1) v += __shfl_xor(v, dd, 64);
    if ((threadIdx.x & 63) == 0) red[threadIdx.x >> 6] = v;
    __syncthreads();
    if (threadIdx.x == 0)
        partial[blockIdx.x] = (red[0] + red[1]) + (red[2] + red[3]);
}

// ---- kernel 2b: final reduce ----
__global__ void k_fin2(const float* __restrict__ partial, float* __restrict__ out) {
    float v = (threadIdx.x < 32) ? partial[threadIdx.x] : 0.f;
#pragma unroll
    for (int d = 1; d < 32; d <<= 1) v += __shfl_xor(v, d, 64);
    if (threadIdx.x == 0) out[0] = v * (1.f / 8192.f);
}

extern "C" void kernel_launch(void* const* d_in, const int* in_sizes, int n_in,
                              void* d_out, int out_size, void* d_ws, size_t ws_size,
                              hipStream_t stream) {
    const float* q = (const float*)d_in[0];
    const float* g = (const float*)d_in[1];
    char* ws = (char*)d_ws;
    uint4* qb     = (uint4*)ws;                                // 4 MiB
    uint4* gb     = (uint4*)(ws + (4u << 20));                 // 4 MiB
    float* diag   = (float*)(ws + (8u << 20));                 // 32 KiB
    float* zpart  = (float*)(ws + (8u << 20) + (32u << 10));   // 512 KiB
    float* partial= (float*)(ws + (8u << 20) + (576u << 10));  // 128 B
    k_cvt <<<2048, 256, 0, stream>>>(q, g, qb, gb);
    k_main<<<512,  256, 0, stream>>>(qb, gb, zpart, diag);
    k_fin1<<<32,   256, 0, stream>>>(zpart, diag, partial);
    k_fin2<<<1,     64, 0, stream>>>(partial, (float*)d_out);
    (void)in_sizes; (void)n_in; (void)out_size; (void)ws_size;
}